// Round 1
// baseline (122.317 us; speedup 1.0000x reference)
//
#include <hip/hip_runtime.h>
#include <hip/hip_bf16.h>

// Problem constants (fixed by setup_inputs)
#define FIN 250
#define NROWS 129024            // 2048*63 nodes
#define NSTRIPES (NROWS / 16)   // 8064 stripes of 16 rows
#define TOTXF (NROWS * FIN)     // 32256000 floats in x
#define NWAVES_TOTAL 1024       // 256 blocks * 4 waves

typedef short short8 __attribute__((ext_vector_type(8)));
typedef float f32x4 __attribute__((ext_vector_type(4)));

__device__ __forceinline__ short f2bf(float f) {
    __bf16 b = (__bf16)f;           // RNE convert
    return __builtin_bit_cast(short, b);
}

// Load one 16-row stripe's A data for this lane: 8 k-steps x 8 floats = 32 float2.
// Lane layout matches the MFMA A-fragment: row = lane&15, k-chunk = (lane>>4)*8.
__device__ __forceinline__ void load_stripe(float2 (&buf)[32], const float* __restrict__ x,
                                            int s, int m, int kg) {
    unsigned fbase = (unsigned)(s * 16 + m) * FIN + (unsigned)(kg * 8);
    #pragma unroll
    for (int kk = 0; kk < 8; ++kk) {
        #pragma unroll
        for (int p = 0; p < 4; ++p) {
            unsigned idx = fbase + (unsigned)(kk * 32 + p * 2);
            // K-pad overreach (k>=250) multiplies zeroed W rows; clamp keeps it in-bounds.
            idx = idx > (TOTXF - 2u) ? (TOTXF - 2u) : idx;
            buf[kk * 4 + p] = *(const float2*)(x + idx);
        }
    }
}

// Compute + store one 16x250 output stripe. wt: bf16 W^T in LDS, [c][k], k-contiguous,
// XOR-swizzled with ((c&7)<<4) inside each 512B row.
__device__ __forceinline__ void compute_stripe(const float2 (&buf)[32],
                                               const unsigned short* wt,
                                               float* __restrict__ out,
                                               int s, int m, int kg, unsigned bswz,
                                               const float (&bcol)[16]) {
    const f32x4 zero = {0.f, 0.f, 0.f, 0.f};
    f32x4 acc[16];
    #pragma unroll
    for (int nf = 0; nf < 16; ++nf) acc[nf] = zero;

    #pragma unroll
    for (int kk = 0; kk < 8; ++kk) {
        short8 af;
        #pragma unroll
        for (int p = 0; p < 4; ++p) {
            af[2 * p]     = f2bf(buf[kk * 4 + p].x);
            af[2 * p + 1] = f2bf(buf[kk * 4 + p].y);
        }
        #pragma unroll
        for (int nf = 0; nf < 16; ++nf) {
            unsigned off = (unsigned)(nf * 16 + m) * 512u
                         + (((unsigned)(kk * 64 + kg * 16)) ^ bswz);
            short8 bf = *(const short8*)((const char*)wt + off);
            acc[nf] = __builtin_amdgcn_mfma_f32_16x16x32_bf16(af, bf, acc[nf], 0, 0, 0);
        }
    }
    // C/D layout: col = lane&15 (=m), row = (lane>>4)*4 + j   [m89-verified]
    unsigned obase = (unsigned)(s * 16 + kg * 4) * FIN + (unsigned)m;
    #pragma unroll
    for (int nf = 0; nf < 16; ++nf) {
        if (nf < 15 || m < 10) {  // mask cols 250..255
            #pragma unroll
            for (int j = 0; j < 4; ++j) {
                out[obase + (unsigned)(j * FIN) + (unsigned)(nf * 16)] = acc[nf][j] + bcol[nf];
            }
        }
    }
}

__global__ void __launch_bounds__(256, 1)
gat_gemm(const float* __restrict__ x, const float* __restrict__ W,
         const float* __restrict__ bias, float* __restrict__ out)
{
    // W^T as bf16, [c (256 rows)][k (256, padded from 250)], 512 B/row, swizzled. 128 KiB.
    __shared__ __align__(16) unsigned short wt[256 * 256];

    const int tid = threadIdx.x;

    // Zero LDS (covers k>=250 pad rows and c>=250 pad cols)
    {
        uint4* p = (uint4*)wt;
        uint4 z = make_uint4(0u, 0u, 0u, 0u);
        #pragma unroll
        for (int i = 0; i < 32; ++i) p[tid + i * 256] = z;
    }
    __syncthreads();

    // Stage W (row-major [k][c] in global) -> wt[c][k] bf16, swizzled
    for (int idx = tid; idx < FIN * FIN; idx += 256) {
        unsigned k = (unsigned)idx / FIN;
        unsigned c = (unsigned)idx - k * FIN;
        unsigned off = (c << 9) + ((2u * k) ^ ((c & 7u) << 4));
        *(unsigned short*)((char*)wt + off) = (unsigned short)f2bf(W[idx]);
    }
    __syncthreads();

    const int lane = tid & 63;
    const int m    = lane & 15;
    const int kg   = lane >> 4;
    const unsigned bswz = ((unsigned)(m & 7)) << 4;
    const int gw   = blockIdx.x * 4 + (tid >> 6);   // global wave id 0..1023

    float bcol[16];
    #pragma unroll
    for (int nf = 0; nf < 16; ++nf) {
        int c = nf * 16 + m;
        bcol[nf] = (c < FIN) ? bias[c] : 0.f;
    }

    // Barrier-free main loop: register ping-pong double buffer across stripes.
    float2 bufA[32], bufB[32];
    int s = gw;
    if (s >= NSTRIPES) return;
    load_stripe(bufA, x, s, m, kg);
    while (true) {
        int sB = s + NWAVES_TOTAL;
        if (sB < NSTRIPES) load_stripe(bufB, x, sB, m, kg);
        compute_stripe(bufA, wt, out, s, m, kg, bswz, bcol);
        if (sB >= NSTRIPES) break;
        int sA = sB + NWAVES_TOTAL;
        if (sA < NSTRIPES) load_stripe(bufA, x, sA, m, kg);
        compute_stripe(bufB, wt, out, sB, m, kg, bswz, bcol);
        if (sA >= NSTRIPES) break;
        s = sA;
    }
}

// Tiny 63-node GAT attention over rows 0..62 of out (which hold h+bias after gat_gemm).
// Single block: internal barriers make read-then-overwrite safe. Since sum(alpha)=1 and
// bias is zero, mixing (h+bias) rows directly reproduces the reference exactly.
__global__ void __launch_bounds__(1024, 1)
gat_attn(const float* __restrict__ att_src, const float* __restrict__ att_dst,
         float* __restrict__ out)
{
    __shared__ float hs[63 * 252];      // h rows 0..62, padded pitch 252
    __shared__ float asrc[64], adst[64];
    __shared__ float alpha[63 * 64];

    const int tid = threadIdx.x;

    for (int idx = tid; idx < 63 * FIN; idx += 1024) {
        int r = idx / FIN, f = idx - r * FIN;
        hs[r * 252 + f] = out[idx];
    }
    __syncthreads();

    if (tid < 63) {
        float s1 = 0.f, s2 = 0.f;
        for (int k = 0; k < FIN; ++k) {
            float h = hs[tid * 252 + k];
            s1 += h * att_src[k];
            s2 += h * att_dst[k];
        }
        asrc[tid] = s1;
        adst[tid] = s2;
    }
    __syncthreads();

    if (tid < 63) {
        float ad = adst[tid];
        float mx = -1e30f;
        for (int sidx = 0; sidx < 63; ++sidx) {
            float e = asrc[sidx] + ad;
            e = e > 0.f ? e : 0.2f * e;       // leaky_relu, slope 0.2
            mx = fmaxf(mx, e);
        }
        float den = 0.f;
        for (int sidx = 0; sidx < 63; ++sidx) {
            float e = asrc[sidx] + ad;
            e = e > 0.f ? e : 0.2f * e;
            float ex = __expf(e - mx);
            alpha[tid * 64 + sidx] = ex;
            den += ex;
        }
        float rd = 1.f / den;
        for (int sidx = 0; sidx < 63; ++sidx) alpha[tid * 64 + sidx] *= rd;
    }
    __syncthreads();

    for (int idx = tid; idx < 63 * FIN; idx += 1024) {
        int d = idx / FIN, f = idx - d * FIN;
        float v = 0.f;
        for (int sidx = 0; sidx < 63; ++sidx)
            v += alpha[d * 64 + sidx] * hs[sidx * 252 + f];
        out[idx] = v;
    }
}

extern "C" void kernel_launch(void* const* d_in, const int* in_sizes, int n_in,
                              void* d_out, int out_size, void* d_ws, size_t ws_size,
                              hipStream_t stream) {
    (void)in_sizes; (void)n_in; (void)d_ws; (void)ws_size; (void)out_size;
    const float* x        = (const float*)d_in[0];
    const float* W        = (const float*)d_in[1];
    const float* att_src  = (const float*)d_in[2];
    const float* att_dst  = (const float*)d_in[3];
    const float* bias     = (const float*)d_in[4];
    float* out            = (float*)d_out;

    gat_gemm<<<256, 256, 0, stream>>>(x, W, bias, out);
    gat_attn<<<1, 1024, 0, stream>>>(att_src, att_dst, out);
}

// Round 2
// 100.243 us; speedup vs baseline: 1.2202x; 1.2202x over previous
//
#include <hip/hip_runtime.h>
#include <hip/hip_bf16.h>

// Problem constants (fixed by setup_inputs)
#define FIN 250
#define NROWS 129024              // 2048*63 nodes
#define NSTRIPES (NROWS / 16)     // 8064 stripes of 16 rows
#define TOTXF (NROWS * FIN)       // 32256000 floats in x
#define NBLOCKS 224
#define WAVES_PER_BLOCK 12
#define NWAVES_TOT (NBLOCKS * WAVES_PER_BLOCK)   // 2688
#define NTASKS (NSTRIPES * 2)                    // 16128 = 2688 * 6 exactly

typedef short short8 __attribute__((ext_vector_type(8)));
typedef float f32x4 __attribute__((ext_vector_type(4)));

__device__ __forceinline__ short f2bf(float f) {
    __bf16 b = (__bf16)f;           // RNE convert
    return __builtin_bit_cast(short, b);
}

// One task = 16 rows x 128 output cols (half = which col-half).
// A-fragment lanes: row = lane&15 (m), k-chunk = (lane>>4)*8 (kg).
__device__ __forceinline__ void do_task(const float* __restrict__ x,
                                        const unsigned short* wt,
                                        float* __restrict__ out,
                                        int stripe, int half, int m, int kg,
                                        unsigned bswz, const float (&bcol)[8]) {
    // ---- load full-K A slice for this lane (32 x float2, transient fp32) ----
    float2 tmp[32];
    unsigned fbase = (unsigned)(stripe * 16 + m) * FIN + (unsigned)(kg * 8);
    #pragma unroll
    for (int kk = 0; kk < 8; ++kk) {
        #pragma unroll
        for (int p = 0; p < 4; ++p) {
            unsigned idx = fbase + (unsigned)(kk * 32 + p * 2);
            // k>=250 pad overreach multiplies zeroed W rows; clamp keeps in-bounds
            idx = idx > (TOTXF - 2u) ? (TOTXF - 2u) : idx;
            tmp[kk * 4 + p] = *(const float2*)(x + idx);
        }
    }
    // ---- convert to bf16 A-fragments (32 VGPRs), fp32 dies here ----
    short8 af[8];
    #pragma unroll
    for (int kk = 0; kk < 8; ++kk) {
        #pragma unroll
        for (int p = 0; p < 4; ++p) {
            af[kk][2 * p]     = f2bf(tmp[kk * 4 + p].x);
            af[kk][2 * p + 1] = f2bf(tmp[kk * 4 + p].y);
        }
    }
    // ---- MFMA: 8 kk x 8 nf, acc = 8 x f32x4 = 32 regs ----
    const f32x4 zero = {0.f, 0.f, 0.f, 0.f};
    f32x4 acc[8];
    #pragma unroll
    for (int nf = 0; nf < 8; ++nf) acc[nf] = zero;

    const unsigned chbase = (unsigned)(half * 128) * 512u;   // col-half base in wt bytes
    #pragma unroll
    for (int kk = 0; kk < 8; ++kk) {
        #pragma unroll
        for (int nf = 0; nf < 8; ++nf) {
            unsigned off = chbase + (unsigned)(nf * 16 + m) * 512u
                         + (((unsigned)(kk * 64 + kg * 16)) ^ bswz);
            short8 bf = *(const short8*)((const char*)wt + off);
            acc[nf] = __builtin_amdgcn_mfma_f32_16x16x32_bf16(af[kk], bf, acc[nf], 0, 0, 0);
        }
    }
    // ---- store: C/D layout col=lane&15(=m), row=(lane>>4)*4+j ----
    unsigned obase = (unsigned)(stripe * 16 + kg * 4) * FIN
                   + (unsigned)(half * 128 + m);
    #pragma unroll
    for (int nf = 0; nf < 8; ++nf) {
        if (half == 0 || nf < 7 || m < 10) {   // mask cols 250..255
            #pragma unroll
            for (int j = 0; j < 4; ++j) {
                out[obase + (unsigned)(j * FIN) + (unsigned)(nf * 16)] = acc[nf][j] + bcol[nf];
            }
        }
    }
}

__global__ void __launch_bounds__(768, 3)
gat_gemm(const float* __restrict__ x, const float* __restrict__ W,
         const float* __restrict__ bias, float* __restrict__ out)
{
    // W^T bf16, [c(256)][k(256 padded)], 512 B/row, XOR-swizzled. 128 KiB.
    __shared__ __align__(16) unsigned short wt[256 * 256];

    const int tid = threadIdx.x;

    // Zero LDS (covers k>=250 and c>=250 pads)
    {
        uint4* p = (uint4*)wt;
        uint4 z = make_uint4(0u, 0u, 0u, 0u);
        for (int i = tid; i < 8192; i += 768) p[i] = z;
    }
    __syncthreads();

    // Stage W (global [k][c] row-major) -> wt[c][k] bf16, swizzled
    for (int idx = tid; idx < FIN * FIN; idx += 768) {
        unsigned k = (unsigned)idx / FIN;
        unsigned c = (unsigned)idx - k * FIN;
        unsigned off = (c << 9) + ((2u * k) ^ ((c & 7u) << 4));
        *(unsigned short*)((char*)wt + off) = (unsigned short)f2bf(W[idx]);
    }
    __syncthreads();

    const int lane = tid & 63;
    const int m    = lane & 15;
    const int kg   = lane >> 4;
    const unsigned bswz = ((unsigned)(m & 7)) << 4;
    const int gw   = blockIdx.x * WAVES_PER_BLOCK + (tid >> 6);

    // Per-task col-half alternates with task id; bcol depends on (half,nf) -> compute per task.
    // Precompute both halves' bias columns cheaply (8 each).
    float bcol0[8], bcol1[8];
    #pragma unroll
    for (int nf = 0; nf < 8; ++nf) {
        int c0 = nf * 16 + m;
        int c1 = 128 + nf * 16 + m;
        bcol0[nf] = bias[c0];                       // c0 <= 127+15 < 250, always valid
        bcol1[nf] = (c1 < FIN) ? bias[c1] : 0.f;
    }

    for (int t = gw; t < NTASKS; t += NWAVES_TOT) {
        int stripe = t >> 1;
        int half   = t & 1;
        if (half == 0)
            do_task(x, wt, out, stripe, 0, m, kg, bswz, bcol0);
        else
            do_task(x, wt, out, stripe, 1, m, kg, bswz, bcol1);
    }
}

// Tiny 63-node GAT attention over rows 0..62 of out (holding h+bias).
// Mixing (h+bias) rows is exact: sum(alpha)=1 -> sum a(h+b) = sum a h + b.
__global__ void __launch_bounds__(1024, 1)
gat_attn(const float* __restrict__ att_src, const float* __restrict__ att_dst,
         float* __restrict__ out)
{
    __shared__ float hs[63 * 252];      // h rows 0..62, padded pitch 252
    __shared__ float asrc[64], adst[64];
    __shared__ float alpha[63 * 64];

    const int tid = threadIdx.x;

    for (int idx = tid; idx < 63 * FIN; idx += 1024) {
        int r = idx / FIN, f = idx - r * FIN;
        hs[r * 252 + f] = out[idx];
    }
    __syncthreads();

    // logits: 16 threads per row, shfl-reduce
    {
        int r = tid >> 4, t = tid & 15;
        float s1 = 0.f, s2 = 0.f;
        if (r < 63) {
            for (int k = t; k < FIN; k += 16) {
                float h = hs[r * 252 + k];
                s1 += h * att_src[k];
                s2 += h * att_dst[k];
            }
        }
        #pragma unroll
        for (int o = 8; o >= 1; o >>= 1) {
            s1 += __shfl_xor(s1, o, 16);
            s2 += __shfl_xor(s2, o, 16);
        }
        if (r < 63 && t == 0) { asrc[r] = s1; adst[r] = s2; }
    }
    __syncthreads();

    // softmax per dst row: 16 threads per row
    {
        int d = tid >> 4, t = tid & 15;
        if (d < 63) {
            float ad = adst[d];
            float e_[4];
            float mx = -1e30f;
            #pragma unroll
            for (int q = 0; q < 4; ++q) {
                int s = t + q * 16;
                float e = -1e30f;
                if (s < 63) {
                    e = asrc[s] + ad;
                    e = e > 0.f ? e : 0.2f * e;     // leaky_relu slope 0.2
                }
                e_[q] = e;
                mx = fmaxf(mx, e);
            }
            #pragma unroll
            for (int o = 8; o >= 1; o >>= 1) mx = fmaxf(mx, __shfl_xor(mx, o, 16));
            float den = 0.f;
            #pragma unroll
            for (int q = 0; q < 4; ++q) {
                int s = t + q * 16;
                float ex = (s < 63) ? __expf(e_[q] - mx) : 0.f;
                e_[q] = ex;
                den += ex;
            }
            #pragma unroll
            for (int o = 8; o >= 1; o >>= 1) den += __shfl_xor(den, o, 16);
            float rd = 1.f / den;
            #pragma unroll
            for (int q = 0; q < 4; ++q) {
                int s = t + q * 16;
                if (s < 63) alpha[d * 64 + s] = e_[q] * rd;
            }
        }
    }
    __syncthreads();

    // mix
    for (int idx = tid; idx < 63 * FIN; idx += 1024) {
        int d = idx / FIN, f = idx - d * FIN;
        float v = 0.f;
        for (int s = 0; s < 63; ++s)
            v += alpha[d * 64 + s] * hs[s * 252 + f];
        out[idx] = v;
    }
}

extern "C" void kernel_launch(void* const* d_in, const int* in_sizes, int n_in,
                              void* d_out, int out_size, void* d_ws, size_t ws_size,
                              hipStream_t stream) {
    (void)in_sizes; (void)n_in; (void)d_ws; (void)ws_size; (void)out_size;
    const float* x        = (const float*)d_in[0];
    const float* W        = (const float*)d_in[1];
    const float* att_src  = (const float*)d_in[2];
    const float* att_dst  = (const float*)d_in[3];
    const float* bias     = (const float*)d_in[4];
    float* out            = (float*)d_out;

    gat_gemm<<<NBLOCKS, 768, 0, stream>>>(x, W, bias, out);
    gat_attn<<<1, 1024, 0, stream>>>(att_src, att_dst, out);
}